// Round 1
// baseline (237.862 us; speedup 1.0000x reference)
//
#include <hip/hip_runtime.h>

// B=8, N=2048, DIN=DOUT=128, DA=2, NEG_SLOPE=0.2
// out[b,i,:] = sum_j mask[b,i,j]*w[b,j]*xv[b,j,:] / sum_j mask[b,i,j]*w[b,j]
//   w[b,j]  = exp( leaky(x@Wc[0])*Wcat[2] + leaky(x@Wc[1])*Wcat[3] )   (lr_row cancels in softmax)
//   xv      = x @ Wx^T + bx

typedef __bf16 bf16x8 __attribute__((ext_vector_type(8)));
typedef __bf16 bf16x4 __attribute__((ext_vector_type(4)));
typedef float  f32x4  __attribute__((ext_vector_type(4)));
typedef int    i32x4  __attribute__((ext_vector_type(4)));

#define MFMA_BF16(a, b, c) __builtin_amdgcn_mfma_f32_16x16x32_bf16((a), (b), (c), 0, 0, 0)

static __device__ __forceinline__ bf16x8 cvt8(f32x4 a, f32x4 b) {
  bf16x8 r;
  r[0] = (__bf16)a[0]; r[1] = (__bf16)a[1]; r[2] = (__bf16)a[2]; r[3] = (__bf16)a[3];
  r[4] = (__bf16)b[0]; r[5] = (__bf16)b[1]; r[6] = (__bf16)b[2]; r[7] = (__bf16)b[3];
  return r;
}

// ---------------------------------------------------------------------------
// Kernel A: per (b, 64 k-rows): compute w[k] and u[k][c] = w[k]*(xv[k][c]),
// write u pre-swizzled in mfma_16x16x32 B-fragment order:
//   elem(b,t,n,lane,j) = u[k = t*32 + (lane>>4)*8 + j][c = n*16 + (lane&15)]
//   at flat index (((b*64+t)*8+n)*64+lane)*8+j
// ---------------------------------------------------------------------------
__global__ __launch_bounds__(256) void prep_kernel(
    const float* __restrict__ x, const float* __restrict__ Wc,
    const float* __restrict__ Wcat, const float* __restrict__ Wx,
    const float* __restrict__ bx, __bf16* __restrict__ u,
    __bf16* __restrict__ wcol)
{
  __shared__ __bf16 lds[8192];  // 16 KB: 2 t-steps x 8 tiles x 64 lanes x 8
  const int blk = blockIdx.x;            // 256 blocks
  const int b = blk >> 5, mt = blk & 31; // 32 blocks/batch, 64 rows each
  const int wv = threadIdx.x >> 6, lane = threadIdx.x & 63;
  const int np = lane & 15, G = lane >> 4;
  const int r0 = mt * 64 + wv * 16;      // wave's 16 k-rows

  // A-fragments: x rows (f32 -> bf16). lane np = row, k = kk*32 + G*8 + j
  const float* xp = x + ((size_t)(b * 2048 + r0 + np)) * 128 + G * 8;
  bf16x8 af[4];
#pragma unroll
  for (int kk = 0; kk < 4; ++kk) {
    f32x4 x0 = *(const f32x4*)(xp + kk * 32);
    f32x4 x1 = *(const f32x4*)(xp + kk * 32 + 4);
    af[kk] = cvt8(x0, x1);
  }

  f32x4 acc[8], accC;
#pragma unroll
  for (int n = 0; n < 8; ++n) { acc[n][0] = 0.f; acc[n][1] = 0.f; acc[n][2] = 0.f; acc[n][3] = 0.f; }
  accC[0] = accC[1] = accC[2] = accC[3] = 0.f;

  // xv = x @ Wx^T : B-frag lane reads Wx[n*16+np][k] (row-major, contiguous k)
#pragma unroll
  for (int n = 0; n < 8; ++n) {
    const float* wp = Wx + (n * 16 + np) * 128 + G * 8;
#pragma unroll
    for (int kk = 0; kk < 4; ++kk) {
      f32x4 w0 = *(const f32x4*)(wp + kk * 32);
      f32x4 w1 = *(const f32x4*)(wp + kk * 32 + 4);
      acc[n] = MFMA_BF16(af[kk], cvt8(w0, w1), acc[n]);
    }
  }
  // Wc tile: cols 0,1 = x . Wc[0], x . Wc[1]
#pragma unroll
  for (int kk = 0; kk < 4; ++kk) {
    bf16x8 bf;
    if (np < 2) {
      const float* cp = Wc + np * 128 + kk * 32 + G * 8;
      f32x4 c0 = *(const f32x4*)cp;
      f32x4 c1 = *(const f32x4*)(cp + 4);
      bf = cvt8(c0, c1);
    } else {
#pragma unroll
      for (int j = 0; j < 8; ++j) bf[j] = (__bf16)0.0f;
    }
    accC = MFMA_BF16(af[kk], bf, accC);
  }

  // epilogue: w = exp(leaky(c0)*a2_0 + leaky(c1)*a2_1), per D-row (= 4G + r)
  const float a20 = Wcat[2], a21 = Wcat[3];
  float wexp[4];
#pragma unroll
  for (int r = 0; r < 4; ++r) {
    float c0 = __shfl(accC[r], lane & 48);        // col 0 of Wc tile
    float c1 = __shfl(accC[r], (lane & 48) | 1);  // col 1
    c0 = c0 > 0.f ? c0 : 0.2f * c0;
    c1 = c1 > 0.f ? c1 : 0.2f * c1;
    wexp[r] = __expf(c0 * a20 + c1 * a21);
  }
  if (np == 0) {  // lanes 0,16,32,48 write w for rows r0+4G+{0..3}
    bf16x4 w4;
#pragma unroll
    for (int r = 0; r < 4; ++r) w4[r] = (__bf16)wexp[r];
    *(bf16x4*)(wcol + (size_t)b * 2048 + r0 + 4 * G) = w4;
  }

  // scatter u values into fragment order via LDS, then linear copy-out.
  // k_in_block = wv*16 + 4G + r  ->  t_rel = wv>>1, g_store = (wv&1)*2 + (G>>1),
  // j = (G&1)*4 + r  (4 consecutive j for r=0..3 -> one b64 write)
  const int t_rel = wv >> 1;
  const int g_store = (wv & 1) * 2 + (G >> 1);
  const int j0 = (G & 1) * 4;
#pragma unroll
  for (int n = 0; n < 8; ++n) {
    float bxv = bx[n * 16 + np];
    bf16x4 v;
#pragma unroll
    for (int r = 0; r < 4; ++r) v[r] = (__bf16)(wexp[r] * (acc[n][r] + bxv));
    *(bf16x4*)(&lds[(t_rel * 8 + n) * 512 + g_store * 128 + np * 8 + j0]) = v;
  }
  __syncthreads();
  __bf16* dst = u + ((size_t)(b * 64 + mt * 2)) * 4096;
#pragma unroll
  for (int it = 0; it < 4; ++it) {
    int s = it * 256 + threadIdx.x;
    ((i32x4*)dst)[s] = ((const i32x4*)lds)[s];  // 16 KB, coalesced
  }
}

// ---------------------------------------------------------------------------
// Kernel B: out = (mask .* w) @ xv / (mask @ w), batched MFMA GEMM.
// 256 blocks (b = blk&7 pins each batch to one XCD's L2), 4 waves/block,
// wave = 16 output rows x 128 cols + denom col. No LDS, no barriers;
// 2-deep register pipeline hides HBM latency on the mask stream.
// ---------------------------------------------------------------------------
__global__ __launch_bounds__(256) void attn_kernel(
    const int* __restrict__ mask, const __bf16* __restrict__ u,
    const __bf16* __restrict__ wcol, float* __restrict__ out)
{
  const int b = blockIdx.x & 7, mt = blockIdx.x >> 3;  // 8 x 32
  const int wv = threadIdx.x >> 6, lane = threadIdx.x & 63;
  const int np = lane & 15, G = lane >> 4;
  const int row0 = mt * 64 + wv * 16;
  const long long N = 2048;

  const int* mp = mask + ((size_t)b * N + row0 + np) * N + G * 8;
  const __bf16* up = u + (size_t)b * 64 * 4096 + lane * 8;  // + t*4096 + n*512
  const __bf16* wp = wcol + (size_t)b * 2048 + G * 8;       // + t*32

  f32x4 acc[9];
#pragma unroll
  for (int n = 0; n < 9; ++n) { acc[n][0] = 0.f; acc[n][1] = 0.f; acc[n][2] = 0.f; acc[n][3] = 0.f; }

  i32x4 m0A, m1A, m0B, m1B;
  bf16x8 ufA[8], ufB[8], wfA, wfB;

#define LOADS(t, m0, m1, uf, wf)                                         \
  do {                                                                   \
    const int* mpt = mp + (t) * 32;                                      \
    m0 = *(const i32x4*)mpt;                                             \
    m1 = *(const i32x4*)(mpt + 4);                                       \
    const __bf16* upt = up + (t) * 4096;                                 \
    _Pragma("unroll")                                                    \
    for (int n = 0; n < 8; ++n) uf[n] = *(const bf16x8*)(upt + n * 512); \
    wf = *(const bf16x8*)(wp + (t) * 32);                                \
  } while (0)

#define COMPS(m0, m1, uf, wf)                                            \
  do {                                                                   \
    const __bf16 ONE = (__bf16)1.0f, ZER = (__bf16)0.0f;                 \
    bf16x8 af;                                                           \
    af[0] = m0[0] ? ONE : ZER; af[1] = m0[1] ? ONE : ZER;                \
    af[2] = m0[2] ? ONE : ZER; af[3] = m0[3] ? ONE : ZER;                \
    af[4] = m1[0] ? ONE : ZER; af[5] = m1[1] ? ONE : ZER;                \
    af[6] = m1[2] ? ONE : ZER; af[7] = m1[3] ? ONE : ZER;                \
    bf16x8 wfrag;                                                        \
    _Pragma("unroll")                                                    \
    for (int j = 0; j < 8; ++j) wfrag[j] = (np == 0) ? wf[j] : ZER;      \
    _Pragma("unroll")                                                    \
    for (int n = 0; n < 8; ++n) acc[n] = MFMA_BF16(af, uf[n], acc[n]);   \
    acc[8] = MFMA_BF16(af, wfrag, acc[8]);                               \
  } while (0)

  LOADS(0, m0A, m1A, ufA, wfA);
  LOADS(1, m0B, m1B, ufB, wfB);
  for (int t = 0; t < 64; t += 2) {
    COMPS(m0A, m1A, ufA, wfA);
    if (t + 2 < 64) LOADS(t + 2, m0A, m1A, ufA, wfA);
    COMPS(m0B, m1B, ufB, wfB);
    if (t + 3 < 64) LOADS(t + 3, m0B, m1B, ufB, wfB);
  }
#undef LOADS
#undef COMPS

  // epilogue: D row i = 4G+r, col = n*16+np; denom = col 0 of tile 8
#pragma unroll
  for (int r = 0; r < 4; ++r) {
    float den = __shfl(acc[8][r], lane & 48);
    float inv = 1.0f / den;
    float* op = out + ((size_t)b * N + row0 + 4 * G + r) * 128 + np;
#pragma unroll
    for (int n = 0; n < 8; ++n) op[n * 16] = acc[n][r] * inv;
  }
}

extern "C" void kernel_launch(void* const* d_in, const int* in_sizes, int n_in,
                              void* d_out, int out_size, void* d_ws, size_t ws_size,
                              hipStream_t stream) {
  const float* x    = (const float*)d_in[0];
  const int*   mask = (const int*)d_in[1];
  // d_in[2] = Wr : unused (lr_row cancels in softmax over j)
  const float* Wc   = (const float*)d_in[3];
  const float* Wcat = (const float*)d_in[4];
  const float* Wx   = (const float*)d_in[5];
  const float* bx   = (const float*)d_in[6];
  float* out = (float*)d_out;

  // workspace: u (8*64*4096 bf16 = 4 MB) + wcol (8*2048 bf16 = 32 KB)
  const size_t U_BYTES = (size_t)8 * 64 * 4096 * 2;
  if (ws_size < U_BYTES + 8 * 2048 * 2) return;  // insufficient scratch
  __bf16* u    = (__bf16*)d_ws;
  __bf16* wcol = (__bf16*)((char*)d_ws + U_BYTES);

  prep_kernel<<<256, 256, 0, stream>>>(x, Wc, Wcat, Wx, bx, u, wcol);
  attn_kernel<<<256, 256, 0, stream>>>(mask, u, wcol, out);
}